// Round 12
// baseline (158.072 us; speedup 1.0000x reference)
//
#include <hip/hip_runtime.h>
#include <math.h>

#define NPTS 65536
#define DIM 64
#define NCODE 1024

typedef float f32x2 __attribute__((ext_vector_type(2)));
typedef float f32x4 __attribute__((ext_vector_type(4)));
typedef short bf16x8 __attribute__((ext_vector_type(8)));

// output layout (flat float32 concat, reference return order)
#define OFF_LOSS 0ull
#define OFF_Q    1ull
#define OFF_PERP 4194305ull
#define OFF_ENC  4194306ull
#define OFF_IDX  71303170ull

__device__ __forceinline__ unsigned short bf16hi(float f) {
    unsigned u = __float_as_uint(f);
    unsigned r = u + 0x7FFFu + ((u >> 16) & 1u);   // RNE truncate to bf16
    return (unsigned short)(r >> 16);
}
__device__ __forceinline__ float bf16tof(unsigned short h) {
    return __uint_as_float(((unsigned)h) << 16);
}

__device__ __forceinline__ void cvt8v(float4 a, float4 b, bf16x8& hi, bf16x8& lo) {
    float v[8] = {a.x, a.y, a.z, a.w, b.x, b.y, b.z, b.w};
#pragma unroll
    for (int i = 0; i < 8; ++i) {
        unsigned short h = bf16hi(v[i]);
        hi[i] = (short)h;
        lo[i] = (short)bf16hi(v[i] - bf16tof(h));
    }
}

// ---------------- fused: MFMA argmin + q_ste + loss + one-hot ----------------
// Block = 4 waves, 64 points (one b,h w-row). KEY CHANGE vs r11: A-fragments
// live in LDS as pre-converted bf16 hi/lo tiles (ds_read_b128 per use) instead
// of 64 resident VGPRs -- the r5..r11 inner loop needed ~175+ live VGPRs and
// spilled (r5/r6 reported VGPR_Count=64 vs ~175 live => compiler shuffled
// A-frags through scratch/accvgpr every ct iteration; occupancy stuck at
// 3 blocks/CU). New live set ~95-100 VGPR -> launch_bounds(256,4), no spill,
// 4 blocks/CU. Scan: wave wv owns codes [256wv,256wv+256), B inline-cvt from
// emb (L2-cached d_in; d_ws is uncached per r5/r6), e2 inline via shfl_xor.
// dist = e2 - 2*(xh.eh + xh.el + xl.eh); packed-u64 argmin (exact first-min).
// Epilogue: idx + hist; NT f32x4 full-row one-hot (r10); q_ste re-reads x
// from global (r8-proven) with plain stores + loss atomic.
__global__ __launch_bounds__(256, 4) void vq_fused(const float* __restrict__ in,
                                                   const float* __restrict__ emb,
                                                   float* __restrict__ out,
                                                   unsigned int* __restrict__ hist,
                                                   float* __restrict__ loss_acc) {
    __shared__ __align__(16) unsigned short lds_hi[64][72];  // [w][d], 144B rows
    __shared__ __align__(16) unsigned short lds_lo[64][72];
    __shared__ unsigned long long cand[4][64];
    __shared__ int s_idx[64];

    const int tid  = threadIdx.x;
    const int lane = tid & 63;
    const int wv   = __builtin_amdgcn_readfirstlane(tid >> 6);

    const int P0 = blockIdx.x * 64;
    const int b  = P0 >> 12;
    const int h  = (P0 >> 6) & 63;
    const float* base = in + (size_t)b * (DIM * 4096) + h * 64;

    // ---- stage x: coalesced fp32 load, cvt to bf16 hi/lo, transpose to LDS ----
    {
        int d  = tid >> 2;
        int wq = tid & 3;
        const float* rowp = base + (size_t)d * 4096 + wq * 16;
#pragma unroll
        for (int j = 0; j < 4; ++j) {
            float4 v = *(const float4*)(rowp + j * 4);
            float vv[4] = {v.x, v.y, v.z, v.w};
#pragma unroll
            for (int i = 0; i < 4; ++i) {
                int w0 = wq * 16 + j * 4 + i;
                unsigned short hb = bf16hi(vv[i]);
                lds_hi[w0][d] = hb;
                lds_lo[w0][d] = bf16hi(vv[i] - bf16tof(hb));
            }
        }
    }
    __syncthreads();

    const int m15 = lane & 15;
    const int g4  = lane >> 4;
    const int kb  = g4 * 8;            // this lane's k-slice base (8 elems)
    const int c0w = wv * 256;          // this wave's code slice (ascending)

    float best[4][4];
    int   bestk[4][4];
#pragma unroll
    for (int pt = 0; pt < 4; ++pt)
#pragma unroll
        for (int r = 0; r < 4; ++r) { best[pt][r] = INFINITY; bestk[pt][r] = 0; }

    for (int ct = 0; ct < 16; ++ct) {
        const int code = c0w + ct * 16 + m15;          // B col = lane&15
        const float* ep = emb + (size_t)code * DIM + kb;
        float4 e0 = *(const float4*)ep;
        float4 e1 = *(const float4*)(ep + 4);
        float4 e2a = *(const float4*)(ep + 32);
        float4 e3 = *(const float4*)(ep + 36);

        // ||e||^2: 16 local squares, then sum the 4 k-slices (xor keeps m15)
        float sq = e0.x * e0.x;
        sq = fmaf(e0.y, e0.y, sq); sq = fmaf(e0.z, e0.z, sq); sq = fmaf(e0.w, e0.w, sq);
        sq = fmaf(e1.x, e1.x, sq); sq = fmaf(e1.y, e1.y, sq); sq = fmaf(e1.z, e1.z, sq); sq = fmaf(e1.w, e1.w, sq);
        sq = fmaf(e2a.x, e2a.x, sq); sq = fmaf(e2a.y, e2a.y, sq); sq = fmaf(e2a.z, e2a.z, sq); sq = fmaf(e2a.w, e2a.w, sq);
        sq = fmaf(e3.x, e3.x, sq); sq = fmaf(e3.y, e3.y, sq); sq = fmaf(e3.z, e3.z, sq); sq = fmaf(e3.w, e3.w, sq);
        sq += __shfl_xor(sq, 16, 64);
        sq += __shfl_xor(sq, 32, 64);
        const float e2v = sq;

        bf16x8 Bhi0, Blo0, Bhi1, Blo1;
        cvt8v(e0, e1, Bhi0, Blo0);
        cvt8v(e2a, e3, Bhi1, Blo1);

#pragma unroll
        for (int pt = 0; pt < 4; ++pt) {
            const int row = pt * 16 + m15;             // A row = lane&15
            bf16x8 ahi0 = *(const bf16x8*)&lds_hi[row][kb];
            bf16x8 ahi1 = *(const bf16x8*)&lds_hi[row][kb + 32];
            bf16x8 alo0 = *(const bf16x8*)&lds_lo[row][kb];
            bf16x8 alo1 = *(const bf16x8*)&lds_lo[row][kb + 32];
            f32x4 acc = {0.f, 0.f, 0.f, 0.f};
            acc = __builtin_amdgcn_mfma_f32_16x16x32_bf16(ahi0, Bhi0, acc, 0, 0, 0);
            acc = __builtin_amdgcn_mfma_f32_16x16x32_bf16(ahi1, Bhi1, acc, 0, 0, 0);
            acc = __builtin_amdgcn_mfma_f32_16x16x32_bf16(ahi0, Blo0, acc, 0, 0, 0);
            acc = __builtin_amdgcn_mfma_f32_16x16x32_bf16(ahi1, Blo1, acc, 0, 0, 0);
            acc = __builtin_amdgcn_mfma_f32_16x16x32_bf16(alo0, Bhi0, acc, 0, 0, 0);
            acc = __builtin_amdgcn_mfma_f32_16x16x32_bf16(alo1, Bhi1, acc, 0, 0, 0);
#pragma unroll
            for (int r = 0; r < 4; ++r) {
                float dist = fmaf(-2.0f, acc[r], e2v);
                if (dist < best[pt][r]) { best[pt][r] = dist; bestk[pt][r] = code; }
            }
        }
    }

    // per-wave cross-lane argmin over 16 cols, lexicographic (dist, code)
#pragma unroll
    for (int pt = 0; pt < 4; ++pt) {
#pragma unroll
        for (int r = 0; r < 4; ++r) {
            unsigned u = __float_as_uint(best[pt][r]);
            u = (u & 0x80000000u) ? ~u : (u | 0x80000000u);   // monotone f32->u32
            unsigned long long key = ((unsigned long long)u << 32) | (unsigned)bestk[pt][r];
#pragma unroll
            for (int sm = 1; sm < 16; sm <<= 1) {
                unsigned long long o = __shfl_xor(key, sm, 16);
                key = (o < key) ? o : key;
            }
            if (m15 == 0) cand[wv][pt * 16 + g4 * 4 + r] = key;
        }
    }
    __syncthreads();

    if (tid < 64) {   // merge 4 wave-slices (ascending -> first-min tie-break)
        unsigned long long k0 = cand[0][tid];
#pragma unroll
        for (int s = 1; s < 4; ++s) {
            unsigned long long o = cand[s][tid];
            if (o < k0) k0 = o;
        }
        int idx = (int)(k0 & 0xFFFFFFFFull);
        s_idx[tid] = idx;
        out[OFF_IDX + P0 + tid] = (float)idx;
        atomicAdd(&hist[idx], 1u);
    }
    __syncthreads();

    // ---- one-hot: wave wv owns rows [16wv,16wv+16); 1024B/wave NT stores ----
    {
        f32x4* enc4 = (f32x4*)(out + OFF_ENC + (unsigned long long)P0 * NCODE);
#pragma unroll
        for (int rr = 0; rr < 16; ++rr) {
            const int row = wv * 16 + rr;              // wave-uniform
            const int target = s_idx[row];
#pragma unroll
            for (int k = 0; k < 4; ++k) {
                const int j = k * 64 + lane;           // f32x4 index in row
                const int c0 = j * 4;
                f32x4 v;
                v.x = (c0 + 0 == target) ? 1.0f : 0.0f;
                v.y = (c0 + 1 == target) ? 1.0f : 0.0f;
                v.z = (c0 + 2 == target) ? 1.0f : 0.0f;
                v.w = (c0 + 3 == target) ? 1.0f : 0.0f;
                __builtin_nontemporal_store(v, &enc4[(size_t)row * 256 + j]);
            }
        }
    }

    // ---- q_ste + loss: wave wv owns dims [16wv,16wv+16); x re-read global ----
    {
        const int w = lane;
        const int myidx = s_idx[w];
        const float* eq = emb + (size_t)myidx * DIM + wv * 16;
        const float* xb = in + ((size_t)b * 64 + wv * 16) * 4096 + h * 64 + w;
        float* qb = out + OFF_Q + ((size_t)b * 64 + wv * 16) * 4096 + h * 64 + w;
        float lsum = 0.f;
#pragma unroll
        for (int dd = 0; dd < 16; ++dd) {
            float x = xb[(size_t)dd * 4096];
            float diff = eq[dd] - x;
            lsum = fmaf(diff, diff, lsum);
            qb[(size_t)dd * 4096] = x + diff;          // exact STE form; plain store
        }
        for (int off = 32; off > 0; off >>= 1) lsum += __shfl_down(lsum, off, 64);
        if (lane == 0) atomicAdd(loss_acc, lsum);
    }
}

// ---------------- finalize: loss scalar + perplexity ----------------
__global__ __launch_bounds__(1024) void vq_finalize(const unsigned int* __restrict__ hist,
                                                    const float* __restrict__ loss_acc,
                                                    float* __restrict__ out) {
    int t = threadIdx.x;
    float c = (float)hist[t];
    float pv = c * (1.0f / (float)NPTS);
    float term = pv * logf(pv + 1e-10f);

    __shared__ float red[16];
    float s = term;
    for (int off = 32; off > 0; off >>= 1) s += __shfl_down(s, off, 64);
    if ((t & 63) == 0) red[t >> 6] = s;
    __syncthreads();
    if (t < 16) {
        float v = red[t];
        for (int off = 8; off > 0; off >>= 1) v += __shfl_down(v, off, 64);
        if (t == 0) {
            out[OFF_PERP] = expf(-v);
            out[OFF_LOSS] = 0.25f * loss_acc[0] * (1.0f / 4194304.0f);
        }
    }
}

extern "C" void kernel_launch(void* const* d_in, const int* in_sizes, int n_in,
                              void* d_out, int out_size, void* d_ws, size_t ws_size,
                              hipStream_t stream) {
    const float* in  = (const float*)d_in[0];   // (16,64,64,64) BCHW
    const float* emb = (const float*)d_in[1];   // (1024,64)
    float* out = (float*)d_out;

    // ws: [0..15] loss_acc f32 | [16..1039] hist u32  (atomics only; no bulk)
    float* ws_f = (float*)d_ws;
    float* loss_acc = ws_f;
    unsigned int* hist = (unsigned int*)d_ws + 16;

    (void)hipMemsetAsync(d_ws, 0, (16 + NCODE) * sizeof(float), stream);

    vq_fused<<<NPTS / 64, 256, 0, stream>>>(in, emb, out, hist, loss_acc);
    vq_finalize<<<1, 1024, 0, stream>>>(hist, loss_acc, out);
}

// Round 13
// 124.355 us; speedup vs baseline: 1.2711x; 1.2711x over previous
//
#include <hip/hip_runtime.h>
#include <math.h>

#define NPTS 65536
#define DIM 64
#define NCODE 1024

typedef float f32x2 __attribute__((ext_vector_type(2)));
typedef float f32x4 __attribute__((ext_vector_type(4)));
typedef short bf16x8 __attribute__((ext_vector_type(8)));

// output layout (flat float32 concat, reference return order)
#define OFF_LOSS 0ull
#define OFF_Q    1ull
#define OFF_PERP 4194305ull
#define OFF_ENC  4194306ull
#define OFF_IDX  71303170ull

__device__ __forceinline__ unsigned short bf16hi(float f) {
    unsigned u = __float_as_uint(f);
    unsigned r = u + 0x7FFFu + ((u >> 16) & 1u);   // RNE truncate to bf16
    return (unsigned short)(r >> 16);
}
__device__ __forceinline__ float bf16tof(unsigned short h) {
    return __uint_as_float(((unsigned)h) << 16);
}

// 8 consecutive fp32 (16B-aligned) -> hi/lo bf16x8
__device__ __forceinline__ void cvt8(const float* p, bf16x8& hi, bf16x8& lo) {
    float4 a = *(const float4*)p;
    float4 b = *(const float4*)(p + 4);
    float v[8] = {a.x, a.y, a.z, a.w, b.x, b.y, b.z, b.w};
#pragma unroll
    for (int i = 0; i < 8; ++i) {
        unsigned short h = bf16hi(v[i]);
        hi[i] = (short)h;
        lo[i] = (short)bf16hi(v[i] - bf16tof(h));
    }
}
__device__ __forceinline__ void cvt8v(float4 a, float4 b, bf16x8& hi, bf16x8& lo) {
    float v[8] = {a.x, a.y, a.z, a.w, b.x, b.y, b.z, b.w};
#pragma unroll
    for (int i = 0; i < 8; ++i) {
        unsigned short h = bf16hi(v[i]);
        hi[i] = (short)h;
        lo[i] = (short)bf16hi(v[i] - bf16tof(h));
    }
}

// ---------------- fused: MFMA argmin + q_ste + loss + one-hot ----------------
// Base = r10 (105.4us best). Two latency cuts in the scan, per r12 counters
// (FETCH/WRITE near-ideal, MfmaUtil 6%, VALUBusy 17% -> dependency-latency
// bound):
//  (1) ||e||^2 hoisted: s_e2[1024] precomputed once per block in LDS; the
//      per-ct 16-FMA chain + 2 serial shfl_xor (~300cyc dependent latency)
//      become one independent ds_read_b32 broadcast.
//  (2) MFMA 6-deep chain split into two independent 3-chains (acc_a/acc_b);
//      dist = e2 - 2*(a+b). 8 chains across 4 pt -> 2x MFMA ILP.
// Everything else identical to r10: x tile fp32 in LDS, A-frags in regs
// (compiler parks in AGPRs, unified file), B inline-cvt from emb (d_in,
// L2-cached; d_ws bulk uncached per r5/r6), packed-u64 argmin, NT f32x4
// full-row one-hot, plain q stores from LDS x.
__global__ __launch_bounds__(256, 3) void vq_fused(const float* __restrict__ in,
                                                   const float* __restrict__ emb,
                                                   float* __restrict__ out,
                                                   unsigned int* __restrict__ hist,
                                                   float* __restrict__ loss_acc) {
    __shared__ __align__(16) float lds_x[64][68];
    __shared__ __align__(16) float s_e2[NCODE];
    __shared__ unsigned long long cand[4][64];
    __shared__ int s_idx[64];

    const int tid  = threadIdx.x;
    const int lane = tid & 63;
    const int wv   = __builtin_amdgcn_readfirstlane(tid >> 6);

    const int P0 = blockIdx.x * 64;
    const int b  = P0 >> 12;
    const int h  = (P0 >> 6) & 63;
    const float* base = in + (size_t)b * (DIM * 4096) + h * 64;

    // ---- stage x: 64x64 fp32 tile, coalesced load, transpose into LDS ----
    {
        int d  = tid >> 2;
        int wq = tid & 3;
        const float* rowp = base + (size_t)d * 4096 + wq * 16;
#pragma unroll
        for (int j = 0; j < 4; ++j) {
            float4 v = *(const float4*)(rowp + j * 4);
            int w0 = wq * 16 + j * 4;
            lds_x[w0 + 0][d] = v.x;
            lds_x[w0 + 1][d] = v.y;
            lds_x[w0 + 2][d] = v.z;
            lds_x[w0 + 3][d] = v.w;
        }
    }

    // ---- s_e2: thread t computes ||e||^2 for codes 4t..4t+3 (L2 hits) ----
    {
        float e2v[4];
#pragma unroll
        for (int c = 0; c < 4; ++c) {
            const float4* ep = (const float4*)(emb + ((size_t)tid * 4 + c) * DIM);
            float s0 = 0.f, s1 = 0.f, s2 = 0.f, s3 = 0.f;
#pragma unroll
            for (int q = 0; q < 16; q += 4) {
                float4 v0 = ep[q], v1 = ep[q + 1], v2 = ep[q + 2], v3 = ep[q + 3];
                s0 = fmaf(v0.x, v0.x, s0); s0 = fmaf(v0.y, v0.y, s0);
                s0 = fmaf(v0.z, v0.z, s0); s0 = fmaf(v0.w, v0.w, s0);
                s1 = fmaf(v1.x, v1.x, s1); s1 = fmaf(v1.y, v1.y, s1);
                s1 = fmaf(v1.z, v1.z, s1); s1 = fmaf(v1.w, v1.w, s1);
                s2 = fmaf(v2.x, v2.x, s2); s2 = fmaf(v2.y, v2.y, s2);
                s2 = fmaf(v2.z, v2.z, s2); s2 = fmaf(v2.w, v2.w, s2);
                s3 = fmaf(v3.x, v3.x, s3); s3 = fmaf(v3.y, v3.y, s3);
                s3 = fmaf(v3.z, v3.z, s3); s3 = fmaf(v3.w, v3.w, s3);
            }
            e2v[c] = ((s0 + s1) + (s2 + s3));
        }
        *(f32x4*)&s_e2[tid * 4] = (f32x4){e2v[0], e2v[1], e2v[2], e2v[3]};
    }
    __syncthreads();

    const int m15 = lane & 15;
    const int g4  = lane >> 4;
    const int kb  = g4 * 8;            // this lane's k-slice base (8 fp32)
    const int c0w = wv * 256;          // this wave's code slice (ascending)

    // A fragments, all 4 point-tiles resident (A row = lane&15, k = kb..)
    bf16x8 Ahi[4][2], Alo[4][2];
#pragma unroll
    for (int pt = 0; pt < 4; ++pt) {
        int p = pt * 16 + m15;
        cvt8(&lds_x[p][kb],      Ahi[pt][0], Alo[pt][0]);
        cvt8(&lds_x[p][kb + 32], Ahi[pt][1], Alo[pt][1]);
    }

    float best[4][4];
    int   bestk[4][4];
#pragma unroll
    for (int pt = 0; pt < 4; ++pt)
#pragma unroll
        for (int r = 0; r < 4; ++r) { best[pt][r] = INFINITY; bestk[pt][r] = 0; }

    for (int ct = 0; ct < 16; ++ct) {
        const int code = c0w + ct * 16 + m15;          // B col = lane&15
        const float* ep = emb + (size_t)code * DIM + kb;
        float4 e0 = *(const float4*)ep;
        float4 e1 = *(const float4*)(ep + 4);
        float4 e2a = *(const float4*)(ep + 32);
        float4 e3 = *(const float4*)(ep + 36);
        const float e2v = s_e2[code];                  // broadcast ds_read

        bf16x8 Bhi0, Blo0, Bhi1, Blo1;
        cvt8v(e0, e1, Bhi0, Blo0);
        cvt8v(e2a, e3, Bhi1, Blo1);

#pragma unroll
        for (int pt = 0; pt < 4; ++pt) {
            f32x4 acc_a = {0.f, 0.f, 0.f, 0.f};
            f32x4 acc_b = {0.f, 0.f, 0.f, 0.f};
            acc_a = __builtin_amdgcn_mfma_f32_16x16x32_bf16(Ahi[pt][0], Bhi0, acc_a, 0, 0, 0);
            acc_b = __builtin_amdgcn_mfma_f32_16x16x32_bf16(Ahi[pt][1], Bhi1, acc_b, 0, 0, 0);
            acc_a = __builtin_amdgcn_mfma_f32_16x16x32_bf16(Ahi[pt][0], Blo0, acc_a, 0, 0, 0);
            acc_b = __builtin_amdgcn_mfma_f32_16x16x32_bf16(Ahi[pt][1], Blo1, acc_b, 0, 0, 0);
            acc_a = __builtin_amdgcn_mfma_f32_16x16x32_bf16(Alo[pt][0], Bhi0, acc_a, 0, 0, 0);
            acc_b = __builtin_amdgcn_mfma_f32_16x16x32_bf16(Alo[pt][1], Bhi1, acc_b, 0, 0, 0);
#pragma unroll
            for (int r = 0; r < 4; ++r) {
                float dist = fmaf(-2.0f, acc_a[r] + acc_b[r], e2v);
                if (dist < best[pt][r]) { best[pt][r] = dist; bestk[pt][r] = code; }
            }
        }
    }

    // per-wave cross-lane argmin over 16 cols, lexicographic (dist, code)
#pragma unroll
    for (int pt = 0; pt < 4; ++pt) {
#pragma unroll
        for (int r = 0; r < 4; ++r) {
            unsigned u = __float_as_uint(best[pt][r]);
            u = (u & 0x80000000u) ? ~u : (u | 0x80000000u);   // monotone f32->u32
            unsigned long long key = ((unsigned long long)u << 32) | (unsigned)bestk[pt][r];
#pragma unroll
            for (int sm = 1; sm < 16; sm <<= 1) {
                unsigned long long o = __shfl_xor(key, sm, 16);
                key = (o < key) ? o : key;
            }
            if (m15 == 0) cand[wv][pt * 16 + g4 * 4 + r] = key;
        }
    }
    __syncthreads();

    if (tid < 64) {   // merge 4 wave-slices (ascending -> first-min tie-break)
        unsigned long long k0 = cand[0][tid];
#pragma unroll
        for (int s = 1; s < 4; ++s) {
            unsigned long long o = cand[s][tid];
            if (o < k0) k0 = o;
        }
        int idx = (int)(k0 & 0xFFFFFFFFull);
        s_idx[tid] = idx;
        out[OFF_IDX + P0 + tid] = (float)idx;
        atomicAdd(&hist[idx], 1u);
    }
    __syncthreads();

    // ---- q_ste + loss: wave wv owns dims [16wv,16wv+16); x from LDS ----
    {
        const int w = lane;
        const int myidx = s_idx[w];
        const float* eq = emb + (size_t)myidx * DIM + wv * 16;
        float* qb = out + OFF_Q + ((size_t)b * 64 + wv * 16) * 4096 + h * 64 + w;
        float lsum = 0.f;
#pragma unroll
        for (int dd = 0; dd < 16; ++dd) {
            float x = lds_x[w][wv * 16 + dd];
            float diff = eq[dd] - x;
            lsum = fmaf(diff, diff, lsum);
            qb[(size_t)dd * 4096] = x + diff;      // exact STE form; plain store
        }
        for (int off = 32; off > 0; off >>= 1) lsum += __shfl_down(lsum, off, 64);
        if (lane == 0) atomicAdd(loss_acc, lsum);
    }

    // ---- one-hot: wave wv owns rows [16wv,16wv+16); 1024B/wave NT stores ----
    {
        f32x4* enc4 = (f32x4*)(out + OFF_ENC + (unsigned long long)P0 * NCODE);
#pragma unroll
        for (int rr = 0; rr < 16; ++rr) {
            const int row = wv * 16 + rr;          // wave-uniform
            const int target = s_idx[row];
#pragma unroll
            for (int k = 0; k < 4; ++k) {
                const int j = k * 64 + lane;       // f32x4 index in row
                const int c0 = j * 4;
                f32x4 v;
                v.x = (c0 + 0 == target) ? 1.0f : 0.0f;
                v.y = (c0 + 1 == target) ? 1.0f : 0.0f;
                v.z = (c0 + 2 == target) ? 1.0f : 0.0f;
                v.w = (c0 + 3 == target) ? 1.0f : 0.0f;
                __builtin_nontemporal_store(v, &enc4[(size_t)row * 256 + j]);
            }
        }
    }
}

// ---------------- finalize: loss scalar + perplexity ----------------
__global__ __launch_bounds__(1024) void vq_finalize(const unsigned int* __restrict__ hist,
                                                    const float* __restrict__ loss_acc,
                                                    float* __restrict__ out) {
    int t = threadIdx.x;
    float c = (float)hist[t];
    float pv = c * (1.0f / (float)NPTS);
    float term = pv * logf(pv + 1e-10f);

    __shared__ float red[16];
    float s = term;
    for (int off = 32; off > 0; off >>= 1) s += __shfl_down(s, off, 64);
    if ((t & 63) == 0) red[t >> 6] = s;
    __syncthreads();
    if (t < 16) {
        float v = red[t];
        for (int off = 8; off > 0; off >>= 1) v += __shfl_down(v, off, 64);
        if (t == 0) {
            out[OFF_PERP] = expf(-v);
            out[OFF_LOSS] = 0.25f * loss_acc[0] * (1.0f / 4194304.0f);
        }
    }
}

extern "C" void kernel_launch(void* const* d_in, const int* in_sizes, int n_in,
                              void* d_out, int out_size, void* d_ws, size_t ws_size,
                              hipStream_t stream) {
    const float* in  = (const float*)d_in[0];   // (16,64,64,64) BCHW
    const float* emb = (const float*)d_in[1];   // (1024,64)
    float* out = (float*)d_out;

    // ws: [0..15] loss_acc f32 | [16..1039] hist u32  (atomics only; no bulk)
    float* ws_f = (float*)d_ws;
    float* loss_acc = ws_f;
    unsigned int* hist = (unsigned int*)d_ws + 16;

    (void)hipMemsetAsync(d_ws, 0, (16 + NCODE) * sizeof(float), stream);

    vq_fused<<<NPTS / 64, 256, 0, stream>>>(in, emb, out, hist, loss_acc);
    vq_finalize<<<1, 1024, 0, stream>>>(hist, loss_acc, out);
}